// Round 14
// baseline (413.973 us; speedup 1.0000x reference)
//
#include <hip/hip_runtime.h>

typedef short bf8_t __attribute__((ext_vector_type(8)));   // 8 x bf16
typedef float f32x4 __attribute__((ext_vector_type(4)));

static constexpr int Bc      = 2;
static constexpr int Nv      = 163842;
static constexpr int CIN     = 64;
static constexpr int COUT    = 64;
static constexpr int KK      = 448;                 // 7*CIN
static constexpr int SEVEN_N = 7 * Nv;              // 1146894; even, %448 = 14
static constexpr int THREADS = 512;                 // 8 waves

// ---- Q=3 m-tiling, d0a-normalized LDS layout ----
static constexpr int LM      = 3 * KK;              // 1344 useful m per tile
static constexpr int MST     = LM + KK;             // 1792 staged (halo)
static constexpr int NT      = (SEVEN_N + LM - 1) / LM;      // 854
static constexpr int NPAIR   = MST / 2;             // 896 m-pairs
static constexpr int CST     = 1352;                // 676 dw; reads ~b128 floor (m134)
static constexpr int TILE_SH = 16 * CST;            // 21632 shorts = 43264 B -> 3 blk/CU

__device__ inline unsigned pack2_bf16(float a, float b) {
    unsigned ua = __builtin_bit_cast(unsigned, a);
    unsigned ub = __builtin_bit_cast(unsigned, b);
    ua = (ua + 0x7FFFu + ((ua >> 16) & 1u)) >> 16;          // RNE
    ub = (ub + 0x7FFFu + ((ub >> 16) & 1u));
    return (ua & 0xFFFFu) | (ub & 0xFFFF0000u);
}

// ---- pre-pass: x fp32 -> PERMUTED bf16 slabs xp[b][cg][v][16ch].
// Slab = Nv*32B = 5.25MB: one XCD's whole gather working set (vs 4MB L2,
// ~76% resident; remainder L3 since xp = 42MB). Decouples L2 footprint from
// concurrent-window count (the r10/r13 failure mode). ----
__global__ __launch_bounds__(256) void xperm(const float* __restrict__ x,
                                             short* __restrict__ xp) {
    const int u = blockIdx.x * 256 + threadIdx.x;
    if (u >= Bc * Nv * 8) return;
    const int b   = (u >= Nv * 8) ? 1 : 0;
    const int rem = u - b * Nv * 8;
    const int v   = rem >> 3;
    const int oct = rem & 7;                         // 8 channels per unit
    const float* src = x + ((size_t)(b * Nv + v) * CIN + oct * 8);
    const float4 a = *(const float4*)(src);
    const float4 c = *(const float4*)(src + 4);
    uint4 o;
    o.x = pack2_bf16(a.x, a.y); o.y = pack2_bf16(a.z, a.w);
    o.z = pack2_bf16(c.x, c.y); o.w = pack2_bf16(c.z, c.w);
    short* dst = xp + ((size_t)((b * 4 + (oct >> 1)) * Nv + v) * 16 + (oct & 1) * 8);
    *(uint4*)dst = o;
}

// ---- main: slot = bid&7 = (cg,b) -> ALL blocks on one XCD read the SAME
// 5.25MB slab (L2-resident), any number of concurrent windows. mt = bid>>3.
// 43.3KB LDS -> 3 blk/CU, 24 waves/CU for gather concurrency. ----
__global__ __launch_bounds__(THREADS, 6) void conv_main_bf16(
    const short* __restrict__ xp,      // permuted slabs
    const short* __restrict__ Wb,      // bf16 W, row-major [COUT][KK]
    const float* __restrict__ bias,
    const int*   __restrict__ idx,
    float*       __restrict__ out)
{
    __shared__ short tile[TILE_SH];                          // 43264 B

    const int bid = blockIdx.x;
    const int s   = bid & 7;           // XCD slot
    const int cg  = s >> 1;
    const int b   = s & 1;
    const int mt  = bid >> 3;          // 0..NT-1

    const int t    = threadIdx.x;
    const int M0   = mt * LM;
    const int mEnd = min(M0 + MST, SEVEN_N);
    const short* xs = xp + (size_t)(b * 4 + cg) * Nv * 16;   // this XCD's slab

    // ---- per-octet d0a chain: d0a(c+1) = (d0a(c) - 14) mod 448, all even ----
    const int q     = t & 1;
    const int pidl  = t >> 1;          // 0..255 pair slot
    const int chb   = cg * 16 + q * 8; // global channel base (for d0a math)

    int d0a_[8];
    {
        int r448 = (int)(((unsigned)chb * (unsigned)SEVEN_N + (unsigned)M0) % 448u);
        #pragma unroll
        for (int j = 0; j < 8; ++j) {
            d0a_[j] = r448 ? 448 - r448 : 0;
            r448 += 14; if (r448 >= 448) r448 -= 448;
        }
    }

    // ---- gather: 2 threads per m-pair, 16B from the 32B vertex strip ----
    int2 ivp[4];
    #pragma unroll
    for (int p = 0; p < 4; ++p) {
        const int pp = p * 256 + pidl;
        const int m0 = M0 + 2 * pp;
        if (pp < NPAIR && m0 + 1 < SEVEN_N) {
            ivp[p] = *(const int2*)(idx + m0);
        } else if (pp < NPAIR && m0 < SEVEN_N) {
            ivp[p].x = idx[m0]; ivp[p].y = idx[m0];
        } else {
            ivp[p].x = 0; ivp[p].y = 0;
        }
    }
    bf8_t v0[4], v1[4];
    #pragma unroll
    for (int p = 0; p < 4; ++p) {
        v0[p] = *(const bf8_t*)(xs + (size_t)ivp[p].x * 16 + q * 8);
        v1[p] = *(const bf8_t*)(xs + (size_t)ivp[p].y * 16 + q * 8);
    }

    // ---- W fragments: L2-resident loads overlap the x-gather drain ----
    const int lane = t & 63;
    const int w    = t >> 6;
    const int col  = lane & 15;
    const int hi   = lane >> 4;
    const int oc   = w & 3;
    const short* wbase = Wb + (oc * 16 + col) * KK + 8 * hi;
    bf8_t bfrag[14];
    #pragma unroll
    for (int k0 = 0; k0 < 14; ++k0)
        bfrag[k0] = *(const bf8_t*)(wbase + 32 * k0);

    // ---- LDS staging: packed b32 at p = dm - d0a(c), bound-predicated ----
    #pragma unroll
    for (int p = 0; p < 4; ++p) {
        const int pp = p * 256 + pidl;
        const int m0 = M0 + 2 * pp;
        if (pp < NPAIR && m0 < mEnd) {
            const int dm = 2 * pp;
            #pragma unroll
            for (int j = 0; j < 8; ++j) {
                const int c  = q * 8 + j;
                const int pj = dm - d0a_[j];
                if ((unsigned)pj < (unsigned)LM) {
                    const unsigned lov = (unsigned short)v0[p][j];
                    const unsigned hiv = (unsigned short)v1[p][j];
                    *(unsigned*)&tile[c * CST + pj] = lov | (hiv << 16);
                }
            }
        }
    }
    __syncthreads();

    // ---- compute: 12 tasks (oc = task&3, r = task>>2) over 8 waves.
    // Reads channel-invariant: tile[col*CST + 448r + 32k0 + 8hi]. ----
    const short* abase0 = &tile[col * CST + 8 * hi];
    const float bo = bias[oc * 16 + col];

    for (int task = w; task < 12; task += 8) {
        const int r = task >> 2;
        const short* abase = abase0 + 448 * r;

        f32x4 acc = (f32x4){0.f, 0.f, 0.f, 0.f};
        #pragma unroll
        for (int k0 = 0; k0 < 14; ++k0) {
            const bf8_t afrag = *(const bf8_t*)(abase + 32 * k0);
            acc = __builtin_amdgcn_mfma_f32_16x16x32_bf16(afrag, bfrag[k0], acc, 0, 0, 0);
        }
        #pragma unroll
        for (int i = 0; i < 4; ++i) {
            const int c_s = 4 * hi + i;
            const int Cs  = cg * 16 + c_s;
            const int Ts  = Cs * SEVEN_N + M0;
            const int d0s = (448 - (Ts % 448)) % 448;
            const int sr  = M0 + d0s + 448 * r;
            if (sr + 448 <= SEVEN_N) {               // skip straddling rows
                const int n = (Ts + d0s) / 448 + r;
                out[((size_t)b * Nv + n) * COUT + oc * 16 + col] = acc[i] + bo;
            }
        }
    }
}

// ---- fallback (r4 structure, fp32 x) if ws too small for the permuted copy ----
static constexpr int STRIDE3 = 1800;
static constexpr int PPP     = THREADS / 4;         // 128
static constexpr int PASSES  = NPAIR / PPP;         // 7

__global__ __launch_bounds__(THREADS, 4) void conv_main_f32(
    const float* __restrict__ x,
    const short* __restrict__ Wb,
    const float* __restrict__ bias,
    const int*   __restrict__ idx,
    float*       __restrict__ out)
{
    __shared__ short tile[16 * STRIDE3];

    const int bid  = blockIdx.x;
    const int slot = bid & 7;
    const int cg   = slot >> 1;
    const int b    = slot & 1;
    const int mt   = bid >> 3;
    const int t    = threadIdx.x;
    const int M0   = mt * LM;
    const int mEnd = min(M0 + MST, SEVEN_N);
    const float* xb = x + (size_t)b * Nv * CIN;

    const int q    = t & 3;
    const int pidl = t >> 2;
    const int xoff = cg * 16 + q * 4;

    int iv0[PASSES], iv1[PASSES];
    #pragma unroll
    for (int p = 0; p < PASSES; ++p) {
        const int m0 = M0 + 2 * (p * PPP + pidl);
        const bool ok = (m0 < mEnd);
        iv0[p] = ok ? idx[m0] : 0;
        iv1[p] = (ok && m0 + 1 < mEnd) ? idx[m0 + 1] : 0;
    }
    float4 v0[PASSES], v1[PASSES];
    #pragma unroll
    for (int p = 0; p < PASSES; ++p) {
        v0[p] = *(const float4*)(xb + (size_t)iv0[p] * CIN + xoff);
        v1[p] = *(const float4*)(xb + (size_t)iv1[p] * CIN + xoff);
    }
    #pragma unroll
    for (int p = 0; p < PASSES; ++p) {
        const int m0 = M0 + 2 * (p * PPP + pidl);
        if (m0 < mEnd) {
            const float a0[4] = {v0[p].x, v0[p].y, v0[p].z, v0[p].w};
            const float a1[4] = {v1[p].x, v1[p].y, v1[p].z, v1[p].w};
            #pragma unroll
            for (int i = 0; i < 4; ++i) {
                const int c     = q * 4 + i;
                const int shift = (6 * c) & 7;
                const int ppos  = (m0 - M0) + shift;
                *(unsigned*)&tile[c * STRIDE3 + ppos] = pack2_bf16(a0[i], a1[i]);
            }
        }
    }
    __syncthreads();

    const int lane = t & 63;
    const int w    = t >> 6;
    const int col  = lane & 15;
    const int hi   = lane >> 4;
    const int oc   = w & 3;

    const short* wbase = Wb + (oc * 16 + col) * KK + 8 * hi;
    bf8_t bfrag[14];
    #pragma unroll
    for (int k0 = 0; k0 < 14; ++k0)
        bfrag[k0] = *(const bf8_t*)(wbase + 32 * k0);

    const int Ca  = cg * 16 + col;
    const int Ta  = Ca * SEVEN_N + M0;
    const int d0a = (448 - (Ta % 448)) % 448;
    const int sha = Ta & 7;
    const short* abase0 = &tile[col * STRIDE3 + d0a + sha + 8 * hi];
    const float bo = bias[oc * 16 + col];

    for (int task = w; task < 12; task += 8) {
        const int r = task >> 2;
        const short* abase = abase0 + 448 * r;
        f32x4 acc = (f32x4){0.f, 0.f, 0.f, 0.f};
        #pragma unroll
        for (int k0 = 0; k0 < 14; ++k0) {
            const bf8_t afrag = *(const bf8_t*)(abase + 32 * k0);
            acc = __builtin_amdgcn_mfma_f32_16x16x32_bf16(afrag, bfrag[k0], acc, 0, 0, 0);
        }
        #pragma unroll
        for (int i = 0; i < 4; ++i) {
            const int c_s = 4 * hi + i;
            const int Cs  = cg * 16 + c_s;
            const int Ts  = Cs * SEVEN_N + M0;
            const int d0s = (448 - (Ts % 448)) % 448;
            const int sr  = M0 + d0s + 448 * r;
            if (sr + 448 <= SEVEN_N) {
                const int n = (Ts + d0s) / 448 + r;
                out[((size_t)b * Nv + n) * COUT + oc * 16 + col] = acc[i] + bo;
            }
        }
    }
}

// Channel-straddling rows (<=63 per batch): exact fp32, j-parallel.
__global__ __launch_bounds__(256) void conv_cleanup(
    const float* __restrict__ x,
    const float* __restrict__ W,
    const float* __restrict__ bias,
    const int*   __restrict__ idx,
    float*       __restrict__ out)
{
    __shared__ float part[4][64];
    const int C = blockIdx.x;
    const int b = blockIdx.y;
    const int t = threadIdx.x;
    const int o = t & 63;
    const int p = t >> 6;
    const int n = (int)(((long long)(C + 1) * SEVEN_N + 447) / 448) - 1;
    const int s = 448 * n - C * SEVEN_N;
    if (s + 448 <= SEVEN_N) return;
    const float* xb = x + (size_t)b * Nv * CIN;
    float acc = 0.f;
    for (int j = p * 112; j < (p + 1) * 112; ++j) {
        int m = s + j, c = C;
        if (m >= SEVEN_N) { m -= SEVEN_N; c += 1; }
        acc += xb[(size_t)idx[m] * CIN + c] * W[o * KK + j];
    }
    part[p][o] = acc;
    __syncthreads();
    if (p == 0)
        out[((size_t)b * Nv + n) * COUT + o] =
            part[0][o] + part[1][o] + part[2][o] + part[3][o] + bias[o];
}

__global__ void wconv(const float* __restrict__ W, short* __restrict__ Wb) {
    const int i = blockIdx.x * 256 + threadIdx.x;
    if (i < COUT * KK) {
        unsigned u = __builtin_bit_cast(unsigned, W[i]);
        u = (u + 0x7FFFu + ((u >> 16) & 1u)) >> 16;
        Wb[i] = (short)u;
    }
}

extern "C" void kernel_launch(void* const* d_in, const int* in_sizes, int n_in,
                              void* d_out, int out_size, void* d_ws, size_t ws_size,
                              hipStream_t stream) {
    const float* x    = (const float*)d_in[0];
    const float* W    = (const float*)d_in[1];
    const float* bias = (const float*)d_in[2];
    const int*   idx  = (const int*)d_in[3];
    float*       out  = (float*)d_out;
    short*       Wb   = (short*)d_ws;                        // [0, 57344)

    hipLaunchKernelGGL(wconv, dim3((COUT * KK + 255) / 256), dim3(256), 0, stream, W, Wb);

    const int    nxe  = Bc * Nv * CIN;                       // 20,971,776
    const size_t need = 65536 + (size_t)nxe * sizeof(short);
    if (ws_size >= need) {
        short* xp = (short*)((char*)d_ws + 65536);
        const int nunits = Bc * Nv * 8;
        hipLaunchKernelGGL(xperm, dim3((nunits + 255) / 256), dim3(256), 0, stream,
                           x, xp);
        hipLaunchKernelGGL(conv_main_bf16, dim3(NT * 8), dim3(THREADS), 0, stream,
                           xp, Wb, bias, idx, out);
    } else {
        hipLaunchKernelGGL(conv_main_f32, dim3(NT * 8), dim3(THREADS), 0, stream,
                           x, Wb, bias, idx, out);
    }
    hipLaunchKernelGGL(conv_cleanup, dim3(CIN, Bc), dim3(256), 0, stream,
                       x, W, bias, idx, out);
}

// Round 16
// 175.182 us; speedup vs baseline: 2.3631x; 2.3631x over previous
//
#include <hip/hip_runtime.h>

typedef short bf8_t __attribute__((ext_vector_type(8)));   // 8 x bf16
typedef float f32x4 __attribute__((ext_vector_type(4)));

static constexpr int Bc      = 2;
static constexpr int Nv      = 163842;
static constexpr int CIN     = 64;
static constexpr int COUT    = 64;
static constexpr int KK      = 448;                 // 7*CIN
static constexpr int SEVEN_N = 7 * Nv;              // 1146894; even, %448 = 14
static constexpr int THREADS = 512;                 // 8 waves

// ---- Q=3 m-tiling, d0a-normalized LDS layout (r11 geometry, best=155us) ----
static constexpr int LM      = 3 * KK;              // 1344 useful m per tile
static constexpr int MST     = LM + KK;             // 1792 staged (halo)
static constexpr int NT      = (SEVEN_N + LM - 1) / LM;      // 854
static constexpr int NPAIR   = MST / 2;             // 896 m-pairs
static constexpr int CST     = 1352;                // 676 dw -> uniform read banks
static constexpr int TILE_AL = 27840;               // 55680 B -> exactly 2 blk/CU
// r11 grid: rr must cover ceil(NT/4)*4 = 856 values so every (mt,cg) pair
// exists (r15 bug: NT*8 lost tiles mt={852,853} x cg={2,3}).
static constexpr int NMAIN   = ((NT + 3) / 4) * 4 * 8;       // 6848
static constexpr int NCLEAN  = CIN * Bc;            // 128 trailing cleanup blocks

// prep kernel split
static constexpr int NXE     = Bc * Nv * CIN;       // 20,971,776
static constexpr int XBLK    = (NXE / 8 + 255) / 256;        // x-convert blocks
static constexpr int WBLK    = (COUT * KK + 255) / 256;      // W-convert blocks

__device__ inline unsigned pack2_bf16(float a, float b) {
    unsigned ua = __builtin_bit_cast(unsigned, a);
    unsigned ub = __builtin_bit_cast(unsigned, b);
    ua = (ua + 0x7FFFu + ((ua >> 16) & 1u)) >> 16;          // RNE
    ub = (ub + 0x7FFFu + ((ub >> 16) & 1u));
    return (ua & 0xFFFFu) | (ub & 0xFFFF0000u);
}

// ---- prep: blocks [0,XBLK) convert x fp32->bf16; [XBLK,XBLK+WBLK) convert W ----
__global__ __launch_bounds__(256) void prep(const float* __restrict__ x,
                                            const float* __restrict__ W,
                                            short* __restrict__ xb,
                                            short* __restrict__ Wb) {
    const int blk = blockIdx.x;
    if (blk < XBLK) {
        const int i = (blk * 256 + threadIdx.x) * 8;
        if (i >= NXE) return;
        const float4 a = *(const float4*)(x + i);
        const float4 c = *(const float4*)(x + i + 4);
        uint4 o;
        o.x = pack2_bf16(a.x, a.y); o.y = pack2_bf16(a.z, a.w);
        o.z = pack2_bf16(c.x, c.y); o.w = pack2_bf16(c.z, c.w);
        *(uint4*)(xb + i) = o;
    } else {
        const int i = (blk - XBLK) * 256 + threadIdx.x;
        if (i < COUT * KK) {
            unsigned u = __builtin_bit_cast(unsigned, W[i]);
            u = (u + 0x7FFFu + ((u >> 16) & 1u)) >> 16;
            Wb[i] = (short)u;
        }
    }
}

// ---- main: blocks [0,NMAIN) = r11 conv path (slot=(mt%4,b) XCD affinity);
// blocks [NMAIN, NMAIN+NCLEAN) = channel-straddle cleanup rows (concurrent
// with the main dispatch instead of a serial launch). ----
__global__ __launch_bounds__(THREADS, 4) void conv_main_bf16(
    const short* __restrict__ xbf,     // (B, Nv, 64) bf16
    const short* __restrict__ Wb,      // bf16 W, row-major [COUT][KK]
    const float* __restrict__ bias,
    const int*   __restrict__ idx,
    const float* __restrict__ xf,      // fp32 x (cleanup path)
    const float* __restrict__ Wf,      // fp32 W (cleanup path)
    float*       __restrict__ out)
{
    __shared__ short tile[TILE_AL];                          // 55680 B -> 2 blk/CU

    const int bid = blockIdx.x;
    const int t   = threadIdx.x;

    if (bid >= NMAIN) {
        // ======== cleanup path: rows straddling a channel boundary ========
        const int bid2 = bid - NMAIN;
        const int C = bid2 & 63;
        const int b = bid2 >> 6;
        const int n = (int)(((long long)(C + 1) * SEVEN_N + 447) / 448) - 1;
        const int s = 448 * n - C * SEVEN_N;
        if (s + 448 <= SEVEN_N) return;          // no straddle at this boundary
        float* part = (float*)tile;              // [8][64] floats
        const int o = t & 63;
        const int p = t >> 6;                    // 0..7, 56 j each
        const float* xbp = xf + (size_t)b * Nv * CIN;
        float acc = 0.f;
        for (int j = p * 56; j < (p + 1) * 56; ++j) {
            int m = s + j, c = C;
            if (m >= SEVEN_N) { m -= SEVEN_N; c += 1; }
            acc += xbp[(size_t)idx[m] * CIN + c] * Wf[o * KK + j];
        }
        part[p * 64 + o] = acc;
        __syncthreads();
        if (p == 0) {
            float r = bias[o];
            #pragma unroll
            for (int k = 0; k < 8; ++k) r += part[k * 64 + o];
            out[((size_t)b * Nv + n) * COUT + o] = r;
        }
        return;
    }

    // ======== main conv path (r11 verbatim) ========
    const int s     = bid & 7;         // XCD slot
    const int b     = s & 1;
    const int mtres = s >> 1;          // mt residue mod 4
    const int rr    = bid >> 3;
    const int mt    = (rr >> 2) * 4 + mtres;
    const int cg    = rr & 3;
    if (mt >= NT) return;

    const int M0   = mt * LM;
    const int mEnd = min(M0 + MST, SEVEN_N);
    const short* xb = xbf + (size_t)b * Nv * CIN;

    // per-octet d0a chain: d0a(c+1) = (d0a(c) - 14) mod 448, all even
    const int q     = t & 1;
    const int pidl  = t >> 1;          // 0..255 pair slot
    const int choff = cg * 16 + q * 8;

    int d0a_[8];
    {
        int r448 = (int)(((unsigned)choff * (unsigned)SEVEN_N + (unsigned)M0) % 448u);
        #pragma unroll
        for (int j = 0; j < 8; ++j) {
            d0a_[j] = r448 ? 448 - r448 : 0;
            r448 += 14; if (r448 >= 448) r448 -= 448;
        }
    }

    // gather: 2 threads per m-pair, ALL pairs (uniform streams)
    int2 ivp[4];
    #pragma unroll
    for (int p = 0; p < 4; ++p) {
        const int pp = p * 256 + pidl;
        const int m0 = M0 + 2 * pp;
        if (pp < NPAIR && m0 + 1 < SEVEN_N) {
            ivp[p] = *(const int2*)(idx + m0);
        } else if (pp < NPAIR && m0 < SEVEN_N) {
            ivp[p].x = idx[m0]; ivp[p].y = idx[m0];
        } else {
            ivp[p].x = 0; ivp[p].y = 0;
        }
    }
    bf8_t v0[4], v1[4];
    #pragma unroll
    for (int p = 0; p < 4; ++p) {
        v0[p] = *(const bf8_t*)(xb + (size_t)ivp[p].x * CIN + choff);
        v1[p] = *(const bf8_t*)(xb + (size_t)ivp[p].y * CIN + choff);
    }

    // W fragments: L2-resident loads overlap the x-gather drain
    const int lane = t & 63;
    const int w    = t >> 6;
    const int col  = lane & 15;
    const int hi   = lane >> 4;
    const int oc   = w & 3;
    const short* wbase = Wb + (oc * 16 + col) * KK + 8 * hi;
    bf8_t bfrag[14];
    #pragma unroll
    for (int k0 = 0; k0 < 14; ++k0)
        bfrag[k0] = *(const bf8_t*)(wbase + 32 * k0);

    // LDS staging: packed b32 at p = dm - d0a(c), bound-predicated
    #pragma unroll
    for (int p = 0; p < 4; ++p) {
        const int pp = p * 256 + pidl;
        const int m0 = M0 + 2 * pp;
        if (pp < NPAIR && m0 < mEnd) {
            const int dm = 2 * pp;
            #pragma unroll
            for (int j = 0; j < 8; ++j) {
                const int c  = q * 8 + j;
                const int pj = dm - d0a_[j];
                if ((unsigned)pj < (unsigned)LM) {
                    const unsigned lov = (unsigned short)v0[p][j];
                    const unsigned hiv = (unsigned short)v1[p][j];
                    *(unsigned*)&tile[c * CST + pj] = lov | (hiv << 16);
                }
            }
        }
    }
    __syncthreads();

    // compute: 12 tasks (oc = task&3, r = task>>2) over 8 waves; reads
    // channel-invariant: tile[col*CST + 448r + 32k0 + 8hi]
    const short* abase0 = &tile[col * CST + 8 * hi];
    const float bo = bias[oc * 16 + col];

    for (int task = w; task < 12; task += 8) {
        const int r = task >> 2;
        const short* abase = abase0 + 448 * r;

        f32x4 acc = (f32x4){0.f, 0.f, 0.f, 0.f};
        #pragma unroll
        for (int k0 = 0; k0 < 14; ++k0) {
            const bf8_t afrag = *(const bf8_t*)(abase + 32 * k0);
            acc = __builtin_amdgcn_mfma_f32_16x16x32_bf16(afrag, bfrag[k0], acc, 0, 0, 0);
        }
        #pragma unroll
        for (int i = 0; i < 4; ++i) {
            const int c_s = 4 * hi + i;
            const int Cs  = cg * 16 + c_s;
            const int Ts  = Cs * SEVEN_N + M0;
            const int d0s = (448 - (Ts % 448)) % 448;
            const int sr  = M0 + d0s + 448 * r;
            if (sr + 448 <= SEVEN_N) {               // skip straddling rows
                const int n = (Ts + d0s) / 448 + r;
                out[((size_t)b * Nv + n) * COUT + oc * 16 + col] = acc[i] + bo;
            }
        }
    }
}

// ---- fallback (r4 structure, fp32 x) if ws too small for the bf16 copy ----
static constexpr int STRIDE3 = 1800;
static constexpr int PPP     = THREADS / 4;         // 128
static constexpr int PASSES  = NPAIR / PPP;         // 7

__global__ __launch_bounds__(THREADS, 4) void conv_main_f32(
    const float* __restrict__ x,
    const short* __restrict__ Wb,
    const float* __restrict__ bias,
    const int*   __restrict__ idx,
    float*       __restrict__ out)
{
    __shared__ short tile[16 * STRIDE3];

    const int bid  = blockIdx.x;
    const int slot = bid & 7;
    const int cg   = slot >> 1;
    const int b    = slot & 1;
    const int mt   = bid >> 3;
    const int t    = threadIdx.x;
    const int M0   = mt * LM;
    const int mEnd = min(M0 + MST, SEVEN_N);
    const float* xb = x + (size_t)b * Nv * CIN;

    const int q    = t & 3;
    const int pidl = t >> 2;
    const int xoff = cg * 16 + q * 4;

    int iv0[PASSES], iv1[PASSES];
    #pragma unroll
    for (int p = 0; p < PASSES; ++p) {
        const int m0 = M0 + 2 * (p * PPP + pidl);
        const bool ok = (m0 < mEnd);
        iv0[p] = ok ? idx[m0] : 0;
        iv1[p] = (ok && m0 + 1 < mEnd) ? idx[m0 + 1] : 0;
    }
    float4 v0[PASSES], v1[PASSES];
    #pragma unroll
    for (int p = 0; p < PASSES; ++p) {
        v0[p] = *(const float4*)(xb + (size_t)iv0[p] * CIN + xoff);
        v1[p] = *(const float4*)(xb + (size_t)iv1[p] * CIN + xoff);
    }
    #pragma unroll
    for (int p = 0; p < PASSES; ++p) {
        const int m0 = M0 + 2 * (p * PPP + pidl);
        if (m0 < mEnd) {
            const float a0[4] = {v0[p].x, v0[p].y, v0[p].z, v0[p].w};
            const float a1[4] = {v1[p].x, v1[p].y, v1[p].z, v1[p].w};
            #pragma unroll
            for (int i = 0; i < 4; ++i) {
                const int c     = q * 4 + i;
                const int shift = (6 * c) & 7;
                const int ppos  = (m0 - M0) + shift;
                *(unsigned*)&tile[c * STRIDE3 + ppos] = pack2_bf16(a0[i], a1[i]);
            }
        }
    }
    __syncthreads();

    const int lane = t & 63;
    const int w    = t >> 6;
    const int col  = lane & 15;
    const int hi   = lane >> 4;
    const int oc   = w & 3;

    const short* wbase = Wb + (oc * 16 + col) * KK + 8 * hi;
    bf8_t bfrag[14];
    #pragma unroll
    for (int k0 = 0; k0 < 14; ++k0)
        bfrag[k0] = *(const bf8_t*)(wbase + 32 * k0);

    const int Ca  = cg * 16 + col;
    const int Ta  = Ca * SEVEN_N + M0;
    const int d0a = (448 - (Ta % 448)) % 448;
    const int sha = Ta & 7;
    const short* abase0 = &tile[col * STRIDE3 + d0a + sha + 8 * hi];
    const float bo = bias[oc * 16 + col];

    for (int task = w; task < 12; task += 8) {
        const int r = task >> 2;
        const short* abase = abase0 + 448 * r;
        f32x4 acc = (f32x4){0.f, 0.f, 0.f, 0.f};
        #pragma unroll
        for (int k0 = 0; k0 < 14; ++k0) {
            const bf8_t afrag = *(const bf8_t*)(abase + 32 * k0);
            acc = __builtin_amdgcn_mfma_f32_16x16x32_bf16(afrag, bfrag[k0], acc, 0, 0, 0);
        }
        #pragma unroll
        for (int i = 0; i < 4; ++i) {
            const int c_s = 4 * hi + i;
            const int Cs  = cg * 16 + c_s;
            const int Ts  = Cs * SEVEN_N + M0;
            const int d0s = (448 - (Ts % 448)) % 448;
            const int sr  = M0 + d0s + 448 * r;
            if (sr + 448 <= SEVEN_N) {
                const int n = (Ts + d0s) / 448 + r;
                out[((size_t)b * Nv + n) * COUT + oc * 16 + col] = acc[i] + bo;
            }
        }
    }
}

// standalone cleanup (fallback path only)
__global__ __launch_bounds__(256) void conv_cleanup(
    const float* __restrict__ x,
    const float* __restrict__ W,
    const float* __restrict__ bias,
    const int*   __restrict__ idx,
    float*       __restrict__ out)
{
    __shared__ float part[4][64];
    const int C = blockIdx.x;
    const int b = blockIdx.y;
    const int t = threadIdx.x;
    const int o = t & 63;
    const int p = t >> 6;
    const int n = (int)(((long long)(C + 1) * SEVEN_N + 447) / 448) - 1;
    const int s = 448 * n - C * SEVEN_N;
    if (s + 448 <= SEVEN_N) return;
    const float* xb = x + (size_t)b * Nv * CIN;
    float acc = 0.f;
    for (int j = p * 112; j < (p + 1) * 112; ++j) {
        int m = s + j, c = C;
        if (m >= SEVEN_N) { m -= SEVEN_N; c += 1; }
        acc += xb[(size_t)idx[m] * CIN + c] * W[o * KK + j];
    }
    part[p][o] = acc;
    __syncthreads();
    if (p == 0)
        out[((size_t)b * Nv + n) * COUT + o] =
            part[0][o] + part[1][o] + part[2][o] + part[3][o] + bias[o];
}

extern "C" void kernel_launch(void* const* d_in, const int* in_sizes, int n_in,
                              void* d_out, int out_size, void* d_ws, size_t ws_size,
                              hipStream_t stream) {
    const float* x    = (const float*)d_in[0];
    const float* W    = (const float*)d_in[1];
    const float* bias = (const float*)d_in[2];
    const int*   idx  = (const int*)d_in[3];
    float*       out  = (float*)d_out;
    short*       Wb   = (short*)d_ws;                        // [0, 57344)

    const size_t need = 65536 + (size_t)NXE * sizeof(short);
    if (ws_size >= need) {
        short* xbf = (short*)((char*)d_ws + 65536);
        hipLaunchKernelGGL(prep, dim3(XBLK + WBLK), dim3(256), 0, stream,
                           x, W, xbf, Wb);
        hipLaunchKernelGGL(conv_main_bf16, dim3(NMAIN + NCLEAN), dim3(THREADS), 0, stream,
                           xbf, Wb, bias, idx, x, W, out);
    } else {
        hipLaunchKernelGGL(prep, dim3(XBLK + WBLK), dim3(256), 0, stream,
                           x, W, (short*)d_ws /*unused xbf slot*/, Wb);
        hipLaunchKernelGGL(conv_main_f32, dim3(NT * 8), dim3(THREADS), 0, stream,
                           x, Wb, bias, idx, out);
        hipLaunchKernelGGL(conv_cleanup, dim3(CIN, Bc), dim3(256), 0, stream,
                           x, W, bias, idx, out);
    }
}